// Round 4
// baseline (214.914 us; speedup 1.0000x reference)
//
#include <hip/hip_runtime.h>
#include <hip/hip_bf16.h>

// SelfAttention B=4 S=2048 D=1024:
//   out = softmax((xWq^T+bq)(xWk^T+bk)^T / 32) (xWv^T+bv)
// 8-phase pipelined bf16 MFMA GEMMs: counted vmcnt(4) only at buffer
// transitions (loads fly >=3 phases), wait-then-barrier for cross-wave LDS
// visibility, chunk-XOR LDS swizzle (measured 0 conflicts), setprio around
// MFMA clusters, NO XCD swizzle (default order had 5x less FETCH).
// ws: xb[8192*1024]bf16 | wqkv[3][1024*1024]bf16 contig | qb,kb[8192*1024]bf16 |
//     vtb[4][1024][2048]bf16 | sc[nb][2048*2048]fp32 (softmax writes bf16 P
//     in-place at row stride 4096 bf16)

typedef __hip_bfloat16 bf16;
typedef __attribute__((ext_vector_type(8))) short bf16x8;
typedef __attribute__((ext_vector_type(4))) float f32x4;
typedef __attribute__((ext_vector_type(4))) short short4v;

__device__ __forceinline__ void gload16(const bf16* g, bf16* l) {
  __builtin_amdgcn_global_load_lds(
      (const __attribute__((address_space(1))) void*)g,
      (__attribute__((address_space(3))) void*)l, 16, 0, 0);
}

#define WAITV(N) asm volatile("s_waitcnt vmcnt(" #N ")" ::: "memory")
#define LGKM0    asm volatile("s_waitcnt lgkmcnt(0)" ::: "memory")
#define SCHED0   __builtin_amdgcn_sched_barrier(0)
#define BAR      __builtin_amdgcn_s_barrier()
#define PRIO1    __builtin_amdgcn_s_setprio(1)
#define PRIO0    __builtin_amdgcn_s_setprio(0)

__global__ __launch_bounds__(256)
void cast_f32_to_bf16(const float* __restrict__ in, bf16* __restrict__ out) {
  long i = ((long)blockIdx.x * blockDim.x + threadIdx.x) * 4;
  float4 f = *(const float4*)(in + i);
  bf16 tmp[4];
  tmp[0] = __float2bfloat16(f.x);
  tmp[1] = __float2bfloat16(f.y);
  tmp[2] = __float2bfloat16(f.z);
  tmp[3] = __float2bfloat16(f.w);
  *(short4v*)(out + i) = *(short4v*)tmp;
}

// ======================= BM=256 BN=256 BK=64, 512 thr ======================
// 8 waves (2M x 4N), per-wave 128x64 = 8m x 4n frags. 2 K-tiles per loop iter,
// 8 phases, 16 MFMA each. Even tiles in buf0, odd in buf1 (no swap).
// Stage: t+1 halves at ph0 (A0,B0) and ph1 (A1,B1); t+2 at ph4, ph5.
// Waits: vmcnt(4) at ph0 (clears tile t) and ph4 (clears t+1), wait->barrier.
// LDS chunk swizzle: 16B chunk of (row r, kchunk j) stored at j^(r&7)
// (storage linear, source pre-swizzled, ds_read applies same XOR).
// OMODE 0: Cf[row][ldc] = scale * A Bt^T, z-strided (sA,sB,sC).
// OMODE 1: QKV combo, N=3072: col>>10 picks {Q,K,V}; Q,K bf16 [8192][1024]
//          (+bias); V stored transposed vtb[(b*1024+c)*2048 + s] (+bias).
template<int OMODE>
__global__ __launch_bounds__(512)
void gemm256(const bf16* __restrict__ A, const bf16* __restrict__ Bt,
             int K, int lda, int ldb,
             float* __restrict__ Cf, int ldc, float scale,
             long sA, long sB, long sC,
             bf16* __restrict__ qout, bf16* __restrict__ kout,
             bf16* __restrict__ vtout,
             const float* __restrict__ bqp, const float* __restrict__ bkp,
             const float* __restrict__ bvp)
{
  __shared__ __align__(16) bf16 As[2][256 * 64];
  __shared__ __align__(16) bf16 Bs[2][256 * 64];
  const int tid = threadIdx.x;
  const int wid = tid >> 6, lane = tid & 63, l15 = lane & 15, kg = lane >> 4;
  const int wr = wid >> 2, wc = wid & 3;
  const int bz = blockIdx.z;
  const long bm = (long)blockIdx.x * 256, bn = (long)blockIdx.y * 256;
  const bf16* Ab = A + (long)bz * sA;
  const bf16* Bb = Bt + (long)bz * sB;

  // staging: 8 slots = {A0,A1,B0,B1} x {l0,l1}; chunk c -> row c>>3, stored
  // kchunk c&7, source kchunk j = (c&7)^(r&7).
  const bf16* gsrc[8];
  int ldst[8];
#pragma unroll
  for (int g = 0; g < 8; ++g) {
    const bool isB = g >= 4;
    const int half = (g >> 1) & 1;
    const int l = g & 1;
    const int c = half * 1024 + l * 512 + tid;
    const int r = c >> 3;
    const int j = (c & 7) ^ (r & 7);
    gsrc[g] = isB ? (Bb + (bn + r) * (long)ldb + (j << 3))
                  : (Ab + (bm + r) * (long)lda + (j << 3));
    ldst[g] = c << 3;  // element offset (16B chunk * 8)
  }
#define STG2(G, BUF, K0) do {                      \
    gload16(gsrc[G] + (K0), &(BUF)[ldst[G]]);      \
    gload16(gsrc[(G)+1] + (K0), &(BUF)[ldst[(G)+1]]); } while (0)

  bf16x8 af[2][4], b0f[2][2], b1f[2][2];
  f32x4 acc[8][4];
#pragma unroll
  for (int m = 0; m < 8; ++m)
#pragma unroll
    for (int n = 0; n < 4; ++n) acc[m][n] = (f32x4){0.f, 0.f, 0.f, 0.f};

#define READ_A(P, MH)                                                   \
  do { _Pragma("unroll") for (int kk = 0; kk < 2; ++kk)                 \
    _Pragma("unroll") for (int mi = 0; mi < 4; ++mi) {                  \
      int row_l = wr * 128 + ((MH) * 4 + mi) * 16 + l15;                \
      int js = ((kk << 2) + kg) ^ (row_l & 7);                          \
      af[kk][mi] = *(const bf16x8*)&(P)[(row_l << 6) + (js << 3)];      \
    } } while (0)
#define READ_B(P, NH, DST)                                              \
  do { _Pragma("unroll") for (int kk = 0; kk < 2; ++kk)                 \
    _Pragma("unroll") for (int ni = 0; ni < 2; ++ni) {                  \
      int row_l = wc * 64 + ((NH) * 2 + ni) * 16 + l15;                 \
      int js = ((kk << 2) + kg) ^ (row_l & 7);                          \
      DST[kk][ni] = *(const bf16x8*)&(P)[(row_l << 6) + (js << 3)];     \
    } } while (0)
#define MFMA16(MH, NH, BF)                                              \
  do { _Pragma("unroll") for (int kk = 0; kk < 2; ++kk)                 \
    _Pragma("unroll") for (int mi = 0; mi < 4; ++mi)                    \
    _Pragma("unroll") for (int ni = 0; ni < 2; ++ni)                    \
      acc[(MH)*4+mi][(NH)*2+ni] = __builtin_amdgcn_mfma_f32_16x16x32_bf16( \
          af[kk][mi], BF[kk][ni], acc[(MH)*4+mi][(NH)*2+ni], 0, 0, 0);  \
  } while (0)

  const int T = K >> 6;  // even (K = 1024 or 2048)
  // prologue: tile 0 -> buf0 (8 loads)
  STG2(0, As[0], 0); STG2(4, Bs[0], 0); STG2(2, As[0], 0); STG2(6, Bs[0], 0);

  for (int t = 0; t < T; t += 2) {
    const int k1 = (t + 1) << 6, k2 = (t + 2) << 6;
    const bool pre = (t + 2) < T;
    // ---- ph0: Q(0,0) of tile t (buf0) ----
    STG2(0, As[1], k1); STG2(4, Bs[1], k1);  // t+1: A0,B0 -> buf1
    WAITV(4);                                 // tile t fully landed
    BAR;
    READ_A(As[0], 0); READ_B(Bs[0], 0, b0f);
    LGKM0; SCHED0; PRIO1; MFMA16(0, 0, b0f); PRIO0; BAR;
    // ---- ph1: Q(0,1) ----
    READ_B(Bs[0], 1, b1f);
    STG2(2, As[1], k1); STG2(6, Bs[1], k1);  // t+1: A1,B1 -> buf1
    BAR; LGKM0; SCHED0; PRIO1; MFMA16(0, 1, b1f); PRIO0; BAR;
    // ---- ph2: Q(1,0) ----
    READ_A(As[0], 1);
    BAR; LGKM0; SCHED0; PRIO1; MFMA16(1, 0, b0f); PRIO0; BAR;
    // ---- ph3: Q(1,1) ----
    PRIO1; MFMA16(1, 1, b1f); PRIO0; BAR;
    // ---- ph4: Q(0,0) of tile t+1 (buf1) ----
    if (pre) { STG2(0, As[0], k2); STG2(4, Bs[0], k2); WAITV(4); }
    else WAITV(0);                            // t+1 fully landed
    BAR;
    READ_A(As[1], 0); READ_B(Bs[1], 0, b0f);
    LGKM0; SCHED0; PRIO1; MFMA16(0, 0, b0f); PRIO0; BAR;
    // ---- ph5: Q(0,1) ----
    READ_B(Bs[1], 1, b1f);
    if (pre) { STG2(2, As[0], k2); STG2(6, Bs[0], k2); }
    BAR; LGKM0; SCHED0; PRIO1; MFMA16(0, 1, b1f); PRIO0; BAR;
    // ---- ph6: Q(1,0) ----
    READ_A(As[1], 1);
    BAR; LGKM0; SCHED0; PRIO1; MFMA16(1, 0, b0f); PRIO0; BAR;
    // ---- ph7: Q(1,1) ----
    PRIO1; MFMA16(1, 1, b1f); PRIO0; BAR;
  }

  // epilogue: C/D frag layout (m89): row = kg*4 + rr, col = l15
#pragma unroll
  for (int m = 0; m < 8; ++m) {
    const long row0 = bm + wr * 128 + m * 16 + (kg << 2);
#pragma unroll
    for (int n = 0; n < 4; ++n) {
      const long col = bn + wc * 64 + n * 16 + l15;
      if constexpr (OMODE == 0) {
        float* C = Cf + (long)bz * sC;
#pragma unroll
        for (int rr = 0; rr < 4; ++rr)
          C[(row0 + rr) * ldc + col] = acc[m][n][rr] * scale;
      } else {
        const int mat = (int)(col >> 10);
        const long c1 = col & 1023;
        if (mat < 2) {
          const float bias_v = (mat ? bkp : bqp)[c1];
          bf16* C = mat ? kout : qout;
#pragma unroll
          for (int rr = 0; rr < 4; ++rr)
            C[(row0 + rr) * 1024 + c1] = __float2bfloat16(acc[m][n][rr] + bias_v);
        } else {
          const float bias_v = bvp[c1];
          const long bb = row0 >> 11;
          const long s0 = row0 & 2047;  // multiple of 4 -> 8B-aligned store
          bf16 tmp[4];
#pragma unroll
          for (int rr = 0; rr < 4; ++rr)
            tmp[rr] = __float2bfloat16(acc[m][n][rr] + bias_v);
          *(short4v*)&vtout[(bb * 1024 + c1) * 2048 + s0] = *(short4v*)tmp;
        }
      }
    }
  }
#undef READ_A
#undef READ_B
#undef MFMA16
#undef STG2
}

// ======================= BM=256 BN=128 BK=64, 512 thr ======================
// PV gemm: 8 waves (2M x 4N), per-wave 128x32 = 8m x 2n. 1 K-tile/iter,
// 2 phases of 16 MFMA. Stage t+1: {A0,B} at ph0 (4 loads), {A1} at ph1 (2).
// Wait vmcnt(4) at ph0 clears tile t (6 loads). C fp32.
__global__ __launch_bounds__(512)
void gemmPV(const bf16* __restrict__ A, const bf16* __restrict__ Bt,
            float* __restrict__ C, int K, int lda, int ldb, int ldc,
            long sA, long sB, long sC)
{
  __shared__ __align__(16) bf16 As[2][256 * 64];
  __shared__ __align__(16) bf16 Bs[2][128 * 64];
  const int tid = threadIdx.x;
  const int wid = tid >> 6, lane = tid & 63, l15 = lane & 15, kg = lane >> 4;
  const int wr = wid >> 2, wc = wid & 3;
  const int bz = blockIdx.z;
  const long bm = (long)blockIdx.x * 256, bn = (long)blockIdx.y * 128;
  const bf16* Ab = A + (long)bz * sA;
  const bf16* Bb = Bt + (long)bz * sB;

  const bf16* gsrc[6];
  int ldst[6];
#pragma unroll
  for (int g = 0; g < 6; ++g) {
    const bool isB = g >= 4;
    const int half = isB ? 0 : (g >> 1);
    const int l = g & 1;
    const int c = half * 1024 + l * 512 + tid;
    const int r = c >> 3;
    const int j = (c & 7) ^ (r & 7);
    gsrc[g] = isB ? (Bb + (bn + r) * (long)ldb + (j << 3))
                  : (Ab + (bm + r) * (long)lda + (j << 3));
    ldst[g] = c << 3;
  }
#define STG2(G, BUF, K0) do {                      \
    gload16(gsrc[G] + (K0), &(BUF)[ldst[G]]);      \
    gload16(gsrc[(G)+1] + (K0), &(BUF)[ldst[(G)+1]]); } while (0)

  bf16x8 af[2][4], bf_[2][2];
  f32x4 acc[8][2];
#pragma unroll
  for (int m = 0; m < 8; ++m)
#pragma unroll
    for (int n = 0; n < 2; ++n) acc[m][n] = (f32x4){0.f, 0.f, 0.f, 0.f};

#define READ_A(P, MH)                                                   \
  do { _Pragma("unroll") for (int kk = 0; kk < 2; ++kk)                 \
    _Pragma("unroll") for (int mi = 0; mi < 4; ++mi) {                  \
      int row_l = wr * 128 + ((MH) * 4 + mi) * 16 + l15;                \
      int js = ((kk << 2) + kg) ^ (row_l & 7);                          \
      af[kk][mi] = *(const bf16x8*)&(P)[(row_l << 6) + (js << 3)];      \
    } } while (0)
#define READ_B(P)                                                       \
  do { _Pragma("unroll") for (int kk = 0; kk < 2; ++kk)                 \
    _Pragma("unroll") for (int ni = 0; ni < 2; ++ni) {                  \
      int row_l = wc * 32 + ni * 16 + l15;                              \
      int js = ((kk << 2) + kg) ^ (row_l & 7);                          \
      bf_[kk][ni] = *(const bf16x8*)&(P)[(row_l << 6) + (js << 3)];     \
    } } while (0)
#define MFMA16(MH)                                                      \
  do { _Pragma("unroll") for (int kk = 0; kk < 2; ++kk)                 \
    _Pragma("unroll") for (int mi = 0; mi < 4; ++mi)                    \
    _Pragma("unroll") for (int ni = 0; ni < 2; ++ni)                    \
      acc[(MH)*4+mi][ni] = __builtin_amdgcn_mfma_f32_16x16x32_bf16(     \
          af[kk][mi], bf_[kk][ni], acc[(MH)*4+mi][ni], 0, 0, 0);        \
  } while (0)

  const int T = K >> 6;
  STG2(0, As[0], 0); STG2(4, Bs[0], 0); STG2(2, As[0], 0);  // tile0: 6 loads

  for (int t = 0; t < T; ++t) {
    bf16* Ac = As[t & 1];
    bf16* Bc = Bs[t & 1];
    bf16* An = As[(t & 1) ^ 1];
    bf16* Bn = Bs[(t & 1) ^ 1];
    const int k1 = (t + 1) << 6;
    const bool pre = (t + 1) < T;
    // ---- ph0 (mh0) ----
    if (pre) { STG2(0, An, k1); STG2(4, Bn, k1); WAITV(4); }
    else WAITV(0);
    BAR;
    READ_A(Ac, 0); READ_B(Bc);
    LGKM0; SCHED0; PRIO1; MFMA16(0); PRIO0; BAR;
    // ---- ph1 (mh1) ----
    READ_A(Ac, 1);
    if (pre) STG2(2, An, k1);
    BAR; LGKM0; SCHED0; PRIO1; MFMA16(1); PRIO0; BAR;
  }

#pragma unroll
  for (int m = 0; m < 8; ++m) {
    const long row0 = bm + wr * 128 + m * 16 + (kg << 2);
#pragma unroll
    for (int n = 0; n < 2; ++n) {
      const long col = bn + wc * 32 + n * 16 + l15;
      float* Cz = C + (long)bz * sC;
#pragma unroll
      for (int rr = 0; rr < 4; ++rr)
        Cz[(row0 + rr) * ldc + col] = acc[m][n][rr];
    }
  }
#undef READ_A
#undef READ_B
#undef MFMA16
#undef STG2
}

// softmax: one block per 2048-col fp32 row; bf16 P written in-place.
__global__ __launch_bounds__(256)
void softmax_inplace_bf16(float* __restrict__ S) {
  float* row = S + (size_t)blockIdx.x * 2048;
  const int tid = threadIdx.x;
  __shared__ float redA[4], redB[4];
  float v[8];
  float mx = -1e30f;
#pragma unroll
  for (int i = 0; i < 8; ++i) {
    v[i] = row[tid + (i << 8)];
    mx = fmaxf(mx, v[i]);
  }
#pragma unroll
  for (int o = 32; o; o >>= 1) mx = fmaxf(mx, __shfl_xor(mx, o));
  if ((tid & 63) == 0) redA[tid >> 6] = mx;
  __syncthreads();
  mx = fmaxf(fmaxf(redA[0], redA[1]), fmaxf(redA[2], redA[3]));
  float sum = 0.f;
#pragma unroll
  for (int i = 0; i < 8; ++i) {
    v[i] = __expf(v[i] - mx);
    sum += v[i];
  }
#pragma unroll
  for (int o = 32; o; o >>= 1) sum += __shfl_xor(sum, o);
  if ((tid & 63) == 0) redB[tid >> 6] = sum;
  __syncthreads();
  sum = redB[0] + redB[1] + redB[2] + redB[3];
  const float inv = 1.f / sum;
  bf16* po = (bf16*)row;
#pragma unroll
  for (int i = 0; i < 8; ++i)
    po[tid + (i << 8)] = __float2bfloat16(v[i] * inv);
}

extern "C" void kernel_launch(void* const* d_in, const int* in_sizes, int n_in,
                              void* d_out, int out_size, void* d_ws, size_t ws_size,
                              hipStream_t stream) {
  const float* x  = (const float*)d_in[0];
  const float* Wq = (const float*)d_in[1];
  const float* bq = (const float*)d_in[2];
  const float* Wk = (const float*)d_in[3];
  const float* bk = (const float*)d_in[4];
  const float* Wv = (const float*)d_in[5];
  const float* bv = (const float*)d_in[6];
  float* out = (float*)d_out;

  const int B = 4, S = 2048, D = 1024;
  const int M = B * S;  // 8192

  bf16* xb  = (bf16*)d_ws;
  bf16* wqb = xb + (size_t)M * D;       // wq,wk,wv contiguous = [3072][1024]
  bf16* qb  = wqb + 3 * (size_t)D * D;
  bf16* kb  = qb + (size_t)M * D;
  bf16* vtb = kb + (size_t)M * D;
  float* sc = (float*)(vtb + (size_t)M * D);

  size_t avail = ws_size - ((size_t)((char*)sc - (char*)d_ws));
  int nb = (int)(avail / ((size_t)S * S * 4));
  if (nb > B) nb = B;
  if (nb < 1) nb = 1;

  // casts
  cast_f32_to_bf16<<<dim3(M * D / 1024), 256, 0, stream>>>(x, xb);
  cast_f32_to_bf16<<<dim3(D * D / 1024), 256, 0, stream>>>(Wq, wqb);
  cast_f32_to_bf16<<<dim3(D * D / 1024), 256, 0, stream>>>(Wk, wqb + (size_t)D * D);
  cast_f32_to_bf16<<<dim3(D * D / 1024), 256, 0, stream>>>(Wv, wqb + 2 * (size_t)D * D);

  // fused QKV projection: one GEMM M=8192, N=3072, K=1024; grid 32x12
  gemm256<1><<<dim3(M / 256, 3 * D / 256, 1), 512, 0, stream>>>(
      xb, wqb, D, D, D, nullptr, 0, 1.f, 0, 0, 0,
      qb, kb, vtb, bq, bk, bv);

  const float iscale = 1.0f / 32.0f;  // 1/sqrt(1024)
  for (int g = 0; g < B; g += nb) {
    const int gn = (g + nb <= B) ? nb : (B - g);
    // QK^T: 256x256 tile, grid 8x8xgn
    gemm256<0><<<dim3(S / 256, S / 256, gn), 512, 0, stream>>>(
        qb + (size_t)g * S * D, kb + (size_t)g * S * D, D, D, D,
        sc, S, iscale, (long)S * D, (long)S * D, (long)S * S,
        nullptr, nullptr, nullptr, nullptr, nullptr, nullptr);
    softmax_inplace_bf16<<<dim3(gn * S), 256, 0, stream>>>(sc);
    // PV: 256x128 tile, K=2048, grid 8x8xgn (P bf16 stride 4096 in sc)
    gemmPV<<<dim3(S / 256, D / 128, gn), 512, 0, stream>>>(
        (const bf16*)sc, vtb + (size_t)g * D * S,
        out + (size_t)g * S * D, S, 2 * S, S, D,
        2L * S * S, (long)D * S, (long)S * D);
  }
}

// Round 5
// 190.792 us; speedup vs baseline: 1.1264x; 1.1264x over previous
//
#include <hip/hip_runtime.h>
#include <hip/hip_bf16.h>

// SelfAttention B=4 S=2048 D=1024:
//   out = softmax((xWq^T+bq)(xWk^T+bk)^T / 32) (xWv^T+bv)
// Round-2 proven structure (128x128 tile, 4 waves, 2-barrier K-loop,
// global_load_lds width-16, chunk-XOR LDS swizzle = measured 0 conflicts,
// ~2.5 blocks/CU TLP) upgraded to 32x32x16 MFMA (half the LDS reads per
// FLOP) and bf16 scores (halves score-buffer HBM round-trip).
// ws: xb[8192*1024]bf16 | wq,wk,wv[1024*1024]bf16 contig | qb,kb[8192*1024]bf16 |
//     vtb[4][1024][2048]bf16 | sc[nb][2048*2048]bf16 (softmax in-place)

typedef __hip_bfloat16 bf16;
typedef __attribute__((ext_vector_type(8))) short bf16x8;
typedef __attribute__((ext_vector_type(16))) float f32x16;
typedef __attribute__((ext_vector_type(4))) short short4v;

__device__ __forceinline__ void gload16(const bf16* g, bf16* l) {
  __builtin_amdgcn_global_load_lds(
      (const __attribute__((address_space(1))) void*)g,
      (__attribute__((address_space(3))) void*)l, 16, 0, 0);
}

__global__ __launch_bounds__(256)
void cast_f32_to_bf16(const float* __restrict__ in, bf16* __restrict__ out) {
  long i = ((long)blockIdx.x * blockDim.x + threadIdx.x) * 4;
  float4 f = *(const float4*)(in + i);
  bf16 tmp[4];
  tmp[0] = __float2bfloat16(f.x);
  tmp[1] = __float2bfloat16(f.y);
  tmp[2] = __float2bfloat16(f.z);
  tmp[3] = __float2bfloat16(f.w);
  *(short4v*)(out + i) = *(short4v*)tmp;
}

// Tile 128x128, 4 waves (2x2, each 64x64 = 2x2 frags of 32x32), BK=64.
// LDS linear [128][64] bf16; 16B chunk (row r, kchunk j) stored at j^(r&7)
// (source pre-swizzled, ds_read applies same XOR; consecutive-8-lane groups
// hit 8 distinct slots -> conflict-free).
// MFMA 32x32x16: A/B frag: row = lane&31, k = (lane>>5)*8 + [0..7].
// C/D frag (m74/m101): col = lane&31, row = (reg&3) + 8*(reg>>2) + 4*(lane>>5).
// OMODE 0: fp32 C = scale*(A Bt^T) at Cout + z*sC            [PV -> out]
// OMODE 1: bf16 C = scale*(A Bt^T) at Cout + z*sC            [QK^T -> scores]
// OMODE 3: QKV combo: z in {0,1,2}: z<2 bf16 [8192][1024]+bias (Q,K);
//          z=2 bf16 transposed vtb[(b*1024+col)*2048+s]+bias (V^T)
template<int OMODE>
__global__ __launch_bounds__(256, 3)
void gemm_bt(const bf16* __restrict__ A, const bf16* __restrict__ Bt,
             const float* __restrict__ b0, const float* __restrict__ b1,
             const float* __restrict__ b2, void* __restrict__ Cout,
             int K, int lda, int ldb, int ldc, float scale,
             long sA, long sB, long sC)
{
  __shared__ __align__(16) bf16 As[128 * 64];
  __shared__ __align__(16) bf16 Bs[128 * 64];
  const int tid = threadIdx.x;
  const int z = blockIdx.z;
  const bf16* Ab = A + (long)z * sA;
  const bf16* Bb = Bt + (long)z * sB;
  const long bm = (long)blockIdx.x * 128;
  const long bn = (long)blockIdx.y * 128;
  const int wid = tid >> 6;
  const int lane = tid & 63;
  const int wr = (wid >> 1) * 64;
  const int wc = (wid & 1) * 64;
  const int fr = lane & 31;   // frag row
  const int kh = lane >> 5;   // k-half (0,1)

  f32x16 acc[2][2];
#pragma unroll
  for (int m = 0; m < 2; ++m)
#pragma unroll
    for (int n = 0; n < 2; ++n)
      acc[m][n] = (f32x16){0.f,0.f,0.f,0.f,0.f,0.f,0.f,0.f,
                           0.f,0.f,0.f,0.f,0.f,0.f,0.f,0.f};

  for (int k0 = 0; k0 < K; k0 += 64) {
    // stage 128x64 of A and Bt: chunk c = i*256+tid; row r=c>>3, source
    // kchunk j = (c&7)^(r&7); LDS dest linear (wave-uniform base + lane*16B).
#pragma unroll
    for (int i = 0; i < 4; ++i) {
      const int c = (i << 8) + tid;
      const int r = c >> 3;
      const int j = (c & 7) ^ (r & 7);
      const int ldsch = (i << 8) + (wid << 6);
      gload16(Ab + (long)(bm + r) * lda + k0 + (j << 3), As + ldsch * 8);
      gload16(Bb + (long)(bn + r) * ldb + k0 + (j << 3), Bs + ldsch * 8);
    }
    __syncthreads();  // drains vmcnt before use
#pragma unroll
    for (int ks = 0; ks < 4; ++ks) {
      bf16x8 af[2], bfv[2];
#pragma unroll
      for (int m = 0; m < 2; ++m) {
        const int row_l = wr + (m << 5) + fr;
        const int js = ((ks << 1) + kh) ^ (row_l & 7);
        af[m] = *(const bf16x8*)&As[(row_l << 6) + (js << 3)];
      }
#pragma unroll
      for (int n = 0; n < 2; ++n) {
        const int row_l = wc + (n << 5) + fr;
        const int js = ((ks << 1) + kh) ^ (row_l & 7);
        bfv[n] = *(const bf16x8*)&Bs[(row_l << 6) + (js << 3)];
      }
#pragma unroll
      for (int m = 0; m < 2; ++m)
#pragma unroll
        for (int n = 0; n < 2; ++n)
          acc[m][n] = __builtin_amdgcn_mfma_f32_32x32x16_bf16(
              af[m], bfv[n], acc[m][n], 0, 0, 0);
    }
    __syncthreads();
  }

  // epilogue
#pragma unroll
  for (int m = 0; m < 2; ++m) {
#pragma unroll
    for (int n = 0; n < 2; ++n) {
      const long col = bn + wc + (n << 5) + fr;
#pragma unroll
      for (int g = 0; g < 4; ++g) {
        const long row0 = bm + wr + (m << 5) + (g << 3) + (kh << 2);
        if constexpr (OMODE == 0) {
          float* C = (float*)Cout + (long)z * sC;
#pragma unroll
          for (int rr = 0; rr < 4; ++rr)
            C[(row0 + rr) * ldc + col] = acc[m][n][(g << 2) + rr] * scale;
        } else if constexpr (OMODE == 1) {
          bf16* C = (bf16*)Cout + (long)z * sC;
#pragma unroll
          for (int rr = 0; rr < 4; ++rr)
            C[(row0 + rr) * ldc + col] =
                __float2bfloat16(acc[m][n][(g << 2) + rr] * scale);
        } else {  // OMODE 3: QKV combo
          const float* bias = (z == 0) ? b0 : (z == 1) ? b1 : b2;
          const float bias_v = bias[col];
          if (z < 2) {
            bf16* C = (bf16*)Cout + (long)z * 8192 * 1024;
#pragma unroll
            for (int rr = 0; rr < 4; ++rr)
              C[(row0 + rr) * 1024 + col] =
                  __float2bfloat16(acc[m][n][(g << 2) + rr] + bias_v);
          } else {
            bf16* C = (bf16*)Cout + 2L * 8192 * 1024;  // vtb
            const long bb = row0 >> 11;
            const long s0 = row0 & 2047;  // multiple of 4 -> 8B-aligned
            bf16 tmp[4];
#pragma unroll
            for (int rr = 0; rr < 4; ++rr)
              tmp[rr] = __float2bfloat16(acc[m][n][(g << 2) + rr] + bias_v);
            *(short4v*)&C[(bb * 1024 + col) * 2048 + s0] = *(short4v*)tmp;
          }
        }
      }
    }
  }
}

// softmax over bf16 score row [2048], in-place (each thread owns 8 contig
// elements; reads before barrier, writes after -> no race).
__global__ __launch_bounds__(256)
void softmax_bf16(bf16* __restrict__ S) {
  bf16* row = S + (size_t)blockIdx.x * 2048;
  const int tid = threadIdx.x;
  __shared__ float redA[4], redB[4];
  bf16x8 in = *(const bf16x8*)(row + (tid << 3));
  float v[8];
  float mx = -1e30f;
#pragma unroll
  for (int i = 0; i < 8; ++i) {
    v[i] = __bfloat162float(((const bf16*)&in)[i]);
    mx = fmaxf(mx, v[i]);
  }
#pragma unroll
  for (int o = 32; o; o >>= 1) mx = fmaxf(mx, __shfl_xor(mx, o));
  if ((tid & 63) == 0) redA[tid >> 6] = mx;
  __syncthreads();
  mx = fmaxf(fmaxf(redA[0], redA[1]), fmaxf(redA[2], redA[3]));
  float sum = 0.f;
#pragma unroll
  for (int i = 0; i < 8; ++i) {
    v[i] = __expf(v[i] - mx);
    sum += v[i];
  }
#pragma unroll
  for (int o = 32; o; o >>= 1) sum += __shfl_xor(sum, o);
  if ((tid & 63) == 0) redB[tid >> 6] = sum;
  __syncthreads();
  sum = redB[0] + redB[1] + redB[2] + redB[3];
  const float inv = 1.f / sum;
  bf16 tmp[8];
#pragma unroll
  for (int i = 0; i < 8; ++i) tmp[i] = __float2bfloat16(v[i] * inv);
  *(bf16x8*)(row + (tid << 3)) = *(bf16x8*)tmp;
}

extern "C" void kernel_launch(void* const* d_in, const int* in_sizes, int n_in,
                              void* d_out, int out_size, void* d_ws, size_t ws_size,
                              hipStream_t stream) {
  const float* x  = (const float*)d_in[0];
  const float* Wq = (const float*)d_in[1];
  const float* bq = (const float*)d_in[2];
  const float* Wk = (const float*)d_in[3];
  const float* bk = (const float*)d_in[4];
  const float* Wv = (const float*)d_in[5];
  const float* bv = (const float*)d_in[6];
  float* out = (float*)d_out;

  const int B = 4, S = 2048, D = 1024;
  const int M = B * S;  // 8192

  bf16* xb  = (bf16*)d_ws;
  bf16* wqb = xb + (size_t)M * D;       // wq,wk,wv contiguous
  bf16* qb  = wqb + 3 * (size_t)D * D;
  bf16* kb  = qb + (size_t)M * D;
  bf16* vtb = kb + (size_t)M * D;
  bf16* sc  = vtb + (size_t)M * D;      // bf16 scores, nb batches

  size_t avail = ws_size - ((size_t)((char*)sc - (char*)d_ws));
  int nb = (int)(avail / ((size_t)S * S * 2));
  if (nb > B) nb = B;
  if (nb < 1) nb = 1;

  // casts
  cast_f32_to_bf16<<<dim3(M * D / 1024), 256, 0, stream>>>(x, xb);
  cast_f32_to_bf16<<<dim3(D * D / 1024), 256, 0, stream>>>(Wq, wqb);
  cast_f32_to_bf16<<<dim3(D * D / 1024), 256, 0, stream>>>(Wk, wqb + (size_t)D * D);
  cast_f32_to_bf16<<<dim3(D * D / 1024), 256, 0, stream>>>(Wv, wqb + 2 * (size_t)D * D);

  // fused QKV projection (z: 0=Q, 1=K, 2=V^T), grid 64x8x3
  gemm_bt<3><<<dim3(M / 128, D / 128, 3), 256, 0, stream>>>(
      xb, wqb, bq, bk, bv, qb, D, D, D, D, 1.f, 0, (long)D * D, 0);

  const float iscale = 1.0f / 32.0f;  // 1/sqrt(1024)
  for (int g = 0; g < B; g += nb) {
    const int gn = (g + nb <= B) ? nb : (B - g);
    // QK^T -> bf16 scores, grid 16x16xgn
    gemm_bt<1><<<dim3(S / 128, S / 128, gn), 256, 0, stream>>>(
        qb + (size_t)g * S * D, kb + (size_t)g * S * D, nullptr, nullptr, nullptr,
        sc, D, D, D, S, iscale, (long)S * D, (long)S * D, (long)S * S);
    softmax_bf16<<<dim3(gn * S), 256, 0, stream>>>(sc);
    // PV: A = P bf16 [2048][2048] in-place, B = vtb [1024][2048], grid 16x8xgn
    gemm_bt<0><<<dim3(S / 128, D / 128, gn), 256, 0, stream>>>(
        sc, vtb + (size_t)g * D * S, nullptr, nullptr, nullptr,
        out + (size_t)g * S * D, S, S, S, D, 1.f,
        (long)S * S, (long)D * S, (long)S * D);
  }
}

// Round 6
// 169.724 us; speedup vs baseline: 1.2663x; 1.1241x over previous
//
#include <hip/hip_runtime.h>
#include <hip/hip_bf16.h>

// SelfAttention B=4 S=2048 D=1024:
//   out = softmax((xWq^T+bq)(xWk^T+bk)^T / 32) (xWv^T+bv)
// Round-2 proven GEMM (16x16x32 MFMA, 128x128 tile, 4 waves, 2-barrier
// K-loop, global_load_lds width-16, chunk-XOR swizzle = measured 0 bank
// conflicts, ~906 TF) + bf16 score path (round-5 proven, halves score
// traffic). No schedule experiments (rounds 3/4 regressed).
// ws: xb[8192*1024]bf16 | wq,wk,wv[1024*1024]bf16 contig | qb,kb[8192*1024]bf16 |
//     vtb[4][1024][2048]bf16 | sc[nb][2048*2048]bf16 (softmax in-place)

typedef __hip_bfloat16 bf16;
typedef __attribute__((ext_vector_type(8))) short bf16x8;
typedef __attribute__((ext_vector_type(4))) float f32x4;
typedef __attribute__((ext_vector_type(4))) short short4v;

__device__ __forceinline__ void gload16(const bf16* g, bf16* l) {
  __builtin_amdgcn_global_load_lds(
      (const __attribute__((address_space(1))) void*)g,
      (__attribute__((address_space(3))) void*)l, 16, 0, 0);
}

__global__ __launch_bounds__(256)
void cast_f32_to_bf16(const float* __restrict__ in, bf16* __restrict__ out) {
  long i = ((long)blockIdx.x * blockDim.x + threadIdx.x) * 4;
  float4 f = *(const float4*)(in + i);
  bf16 tmp[4];
  tmp[0] = __float2bfloat16(f.x);
  tmp[1] = __float2bfloat16(f.y);
  tmp[2] = __float2bfloat16(f.z);
  tmp[3] = __float2bfloat16(f.w);
  *(short4v*)(out + i) = *(short4v*)tmp;
}

// 3 weight matrices in one dispatch (z picks source; dests contiguous).
__global__ __launch_bounds__(256)
void cast3_f32_to_bf16(const float* __restrict__ w0, const float* __restrict__ w1,
                       const float* __restrict__ w2, bf16* __restrict__ out) {
  const float* src = (blockIdx.y == 0) ? w0 : (blockIdx.y == 1) ? w1 : w2;
  long i = ((long)blockIdx.x * blockDim.x + threadIdx.x) * 4;
  float4 f = *(const float4*)(src + i);
  bf16 tmp[4];
  tmp[0] = __float2bfloat16(f.x);
  tmp[1] = __float2bfloat16(f.y);
  tmp[2] = __float2bfloat16(f.z);
  tmp[3] = __float2bfloat16(f.w);
  *(short4v*)(out + (long)blockIdx.y * 1024 * 1024 + i) = *(short4v*)tmp;
}

// Tile 128x128, 4 waves (2x2, each 64x64 = 4x4 frags of 16x16), BK=64.
// LDS linear [128][64] bf16; 16B chunk (row r, kchunk j) stored at j^(r&7)
// (source pre-swizzled, ds_read same XOR; within each 16-lane frag group
// rows 0..15 hit 8 distinct slots twice = 2-way = free; measured 0 conflicts).
// MFMA 16x16x32. C/D frag (m89): row = kg*4 + rr, col = l15.
// OMODE 0: fp32 C = scale*(A Bt^T) + z*sC               [PV -> out]
// OMODE 1: bf16 C = scale*(A Bt^T) + z*sC               [QK^T -> scores]
// OMODE 3: QKV combo: z=0,1: bf16 [8192][1024]+bias (Q,K);
//          z=2: bf16 transposed vtb[(b*1024+col)*2048+s]+bias (V^T)
template<int OMODE>
__global__ __launch_bounds__(256, 3)
void gemm_bt(const bf16* __restrict__ A, const bf16* __restrict__ Bt,
             const float* __restrict__ b0, const float* __restrict__ b1,
             const float* __restrict__ b2, void* __restrict__ Cout,
             int K, int lda, int ldb, int ldc, float scale,
             long sA, long sB, long sC)
{
  __shared__ __align__(16) bf16 As[128 * 64];
  __shared__ __align__(16) bf16 Bs[128 * 64];
  const int tid = threadIdx.x;
  const int z = blockIdx.z;
  const bf16* Ab = A + (long)z * sA;
  const bf16* Bb = Bt + (long)z * sB;
  const long bm = (long)blockIdx.x * 128;
  const long bn = (long)blockIdx.y * 128;
  const int wid = tid >> 6;
  const int lane = tid & 63;
  const int wr = (wid >> 1) * 64;
  const int wc = (wid & 1) * 64;
  const int l15 = lane & 15;
  const int kg = lane >> 4;

  f32x4 acc[4][4];
#pragma unroll
  for (int m = 0; m < 4; ++m)
#pragma unroll
    for (int n = 0; n < 4; ++n)
      acc[m][n] = (f32x4){0.f, 0.f, 0.f, 0.f};

  for (int k0 = 0; k0 < K; k0 += 64) {
    // stage 128x64 of A and Bt: chunk c = i*256+tid; row r=c>>3, source
    // kchunk j=(c&7)^(r&7); LDS dest linear (wave-uniform base + lane*16B).
#pragma unroll
    for (int i = 0; i < 4; ++i) {
      const int c = (i << 8) + tid;
      const int r = c >> 3;
      const int j = (c & 7) ^ (r & 7);
      const int ldsch = (i << 8) + (wid << 6);
      gload16(Ab + (long)(bm + r) * lda + k0 + (j << 3), As + ldsch * 8);
      gload16(Bb + (long)(bn + r) * ldb + k0 + (j << 3), Bs + ldsch * 8);
    }
    __syncthreads();  // drains vmcnt before use
#pragma unroll
    for (int kk = 0; kk < 2; ++kk) {
      bf16x8 af[4], bfv[4];
#pragma unroll
      for (int m = 0; m < 4; ++m) {
        const int row_l = wr + (m << 4) + l15;
        const int js = ((kk << 2) + kg) ^ (row_l & 7);
        af[m] = *(const bf16x8*)&As[(row_l << 6) + (js << 3)];
      }
#pragma unroll
      for (int n = 0; n < 4; ++n) {
        const int row_l = wc + (n << 4) + l15;
        const int js = ((kk << 2) + kg) ^ (row_l & 7);
        bfv[n] = *(const bf16x8*)&Bs[(row_l << 6) + (js << 3)];
      }
#pragma unroll
      for (int m = 0; m < 4; ++m)
#pragma unroll
        for (int n = 0; n < 4; ++n)
          acc[m][n] = __builtin_amdgcn_mfma_f32_16x16x32_bf16(
              af[m], bfv[n], acc[m][n], 0, 0, 0);
    }
    __syncthreads();
  }

  // epilogue: C/D frag layout (m89): row = kg*4 + rr, col = l15
#pragma unroll
  for (int m = 0; m < 4; ++m) {
    const long row0 = bm + wr + (m << 4) + (kg << 2);
#pragma unroll
    for (int n = 0; n < 4; ++n) {
      const long col = bn + wc + (n << 4) + l15;
      if constexpr (OMODE == 0) {
        float* C = (float*)Cout + (long)z * sC;
#pragma unroll
        for (int rr = 0; rr < 4; ++rr)
          C[(row0 + rr) * ldc + col] = acc[m][n][rr] * scale;
      } else if constexpr (OMODE == 1) {
        bf16* C = (bf16*)Cout + (long)z * sC;
#pragma unroll
        for (int rr = 0; rr < 4; ++rr)
          C[(row0 + rr) * ldc + col] = __float2bfloat16(acc[m][n][rr] * scale);
      } else {  // OMODE 3: QKV combo
        const float* bias = (z == 0) ? b0 : (z == 1) ? b1 : b2;
        const float bias_v = bias[col];
        if (z < 2) {
          bf16* C = (bf16*)Cout + (long)z * 8192 * 1024;
#pragma unroll
          for (int rr = 0; rr < 4; ++rr)
            C[(row0 + rr) * 1024 + col] =
                __float2bfloat16(acc[m][n][rr] + bias_v);
        } else {
          bf16* C = (bf16*)Cout + 2L * 8192 * 1024;  // vtb
          const long bb = row0 >> 11;
          const long s0 = row0 & 2047;  // multiple of 4 -> 8B-aligned
          bf16 tmp[4];
#pragma unroll
          for (int rr = 0; rr < 4; ++rr)
            tmp[rr] = __float2bfloat16(acc[m][n][rr] + bias_v);
          *(short4v*)&C[(bb * 1024 + col) * 2048 + s0] = *(short4v*)tmp;
        }
      }
    }
  }
}

// softmax over bf16 score row [2048], in-place (each thread owns its 8
// contiguous elements; no cross-thread aliasing).
__global__ __launch_bounds__(256)
void softmax_bf16(bf16* __restrict__ S) {
  bf16* row = S + (size_t)blockIdx.x * 2048;
  const int tid = threadIdx.x;
  __shared__ float redA[4], redB[4];
  bf16x8 in = *(const bf16x8*)(row + (tid << 3));
  float v[8];
  float mx = -1e30f;
#pragma unroll
  for (int i = 0; i < 8; ++i) {
    v[i] = __bfloat162float(((const bf16*)&in)[i]);
    mx = fmaxf(mx, v[i]);
  }
#pragma unroll
  for (int o = 32; o; o >>= 1) mx = fmaxf(mx, __shfl_xor(mx, o));
  if ((tid & 63) == 0) redA[tid >> 6] = mx;
  __syncthreads();
  mx = fmaxf(fmaxf(redA[0], redA[1]), fmaxf(redA[2], redA[3]));
  float sum = 0.f;
#pragma unroll
  for (int i = 0; i < 8; ++i) {
    v[i] = __expf(v[i] - mx);
    sum += v[i];
  }
#pragma unroll
  for (int o = 32; o; o >>= 1) sum += __shfl_xor(sum, o);
  if ((tid & 63) == 0) redB[tid >> 6] = sum;
  __syncthreads();
  sum = redB[0] + redB[1] + redB[2] + redB[3];
  const float inv = 1.f / sum;
  bf16 tmp[8];
#pragma unroll
  for (int i = 0; i < 8; ++i) tmp[i] = __float2bfloat16(v[i] * inv);
  *(bf16x8*)(row + (tid << 3)) = *(bf16x8*)tmp;
}

extern "C" void kernel_launch(void* const* d_in, const int* in_sizes, int n_in,
                              void* d_out, int out_size, void* d_ws, size_t ws_size,
                              hipStream_t stream) {
  const float* x  = (const float*)d_in[0];
  const float* Wq = (const float*)d_in[1];
  const float* bq = (const float*)d_in[2];
  const float* Wk = (const float*)d_in[3];
  const float* bk = (const float*)d_in[4];
  const float* Wv = (const float*)d_in[5];
  const float* bv = (const float*)d_in[6];
  float* out = (float*)d_out;

  const int B = 4, S = 2048, D = 1024;
  const int M = B * S;  // 8192

  bf16* xb  = (bf16*)d_ws;
  bf16* wqb = xb + (size_t)M * D;       // wq,wk,wv contiguous
  bf16* qb  = wqb + 3 * (size_t)D * D;
  bf16* kb  = qb + (size_t)M * D;
  bf16* vtb = kb + (size_t)M * D;
  bf16* sc  = vtb + (size_t)M * D;      // bf16 scores, nb batches

  size_t avail = ws_size - ((size_t)((char*)sc - (char*)d_ws));
  int nb = (int)(avail / ((size_t)S * S * 2));
  if (nb > B) nb = B;
  if (nb < 1) nb = 1;

  // casts: x (8192 blocks) + all three W in one dispatch (256x3)
  cast_f32_to_bf16<<<dim3(M * D / 1024), 256, 0, stream>>>(x, xb);
  cast3_f32_to_bf16<<<dim3(D * D / 1024, 3), 256, 0, stream>>>(Wq, Wk, Wv, wqb);

  // fused QKV projection (z: 0=Q, 1=K, 2=V^T), grid 64x8x3 = 1536 blocks
  gemm_bt<3><<<dim3(M / 128, D / 128, 3), 256, 0, stream>>>(
      xb, wqb, bq, bk, bv, qb, D, D, D, D, 1.f, 0, (long)D * D, 0);

  const float iscale = 1.0f / 32.0f;  // 1/sqrt(1024)
  for (int g = 0; g < B; g += nb) {
    const int gn = (g + nb <= B) ? nb : (B - g);
    // QK^T -> bf16 scores, grid 16x16xgn
    gemm_bt<1><<<dim3(S / 128, S / 128, gn), 256, 0, stream>>>(
        qb + (size_t)g * S * D, kb + (size_t)g * S * D, nullptr, nullptr, nullptr,
        sc, D, D, D, S, iscale, (long)S * D, (long)S * D, (long)S * S);
    softmax_bf16<<<dim3(gn * S), 256, 0, stream>>>(sc);
    // PV: A = P bf16 [2048][2048], B = vtb [1024][2048], grid 16x8xgn
    gemm_bt<0><<<dim3(S / 128, D / 128, gn), 256, 0, stream>>>(
        sc, vtb + (size_t)g * D * S, nullptr, nullptr, nullptr,
        out + (size_t)g * S * D, S, S, S, D, 1.f,
        (long)S * S, (long)D * S, (long)S * D);
  }
}